// Round 3
// baseline (365.284 us; speedup 1.0000x reference)
//
#include <hip/hip_runtime.h>
#include <stdint.h>

#define M_DIM 4096
#define N_DIM 4096
#define K_DIM 4096

#define BM 128
#define BN 128
#define BK 32
#define KT (K_DIM / BK)  // 128 k-tiles

typedef __bf16 bf16x8 __attribute__((ext_vector_type(8)));
typedef float f32x4 __attribute__((ext_vector_type(4)));
typedef unsigned short us8 __attribute__((ext_vector_type(8)));

// round-to-nearest-even fp32 -> bf16 bits
__device__ __forceinline__ unsigned short f2bf(float f) {
    unsigned u = __builtin_bit_cast(unsigned, f);
    u = (u + 0x7FFFu + ((u >> 16) & 1u)) >> 16;
    return (unsigned short)u;
}

__device__ __forceinline__ us8 cvt8(float4 a, float4 b) {
    us8 o;
    o[0] = f2bf(a.x); o[1] = f2bf(a.y); o[2] = f2bf(a.z); o[3] = f2bf(a.w);
    o[4] = f2bf(b.x); o[5] = f2bf(b.y); o[6] = f2bf(b.z); o[7] = f2bf(b.w);
    return o;
}

// ---------------------------------------------------------------- prep
// W fp32 [K][N] -> Wt bf16 [N][K]; 64x64 tiles, 4096 blocks.
__global__ __launch_bounds__(256) void prep(const float* __restrict__ W,
                                            unsigned short* __restrict__ Wt) {
    __shared__ float tile[64][65];  // +1 pad: store stride-1, read stride-65
    const int b = blockIdx.x;
    const int tid = threadIdx.x;
    const int n0 = (b & 63) * 64;
    const int k0 = (b >> 6) * 64;
    const int c = tid & 63;
    const int r4 = tid >> 6;
#pragma unroll
    for (int rr = 0; rr < 16; ++rr) {
        const int row = r4 * 16 + rr;
        tile[row][c] = W[(size_t)(k0 + row) * N_DIM + (n0 + c)];
    }
    __syncthreads();
    const int kc = tid & 7;
#pragma unroll
    for (int half = 0; half < 2; ++half) {
        const int nrow = (tid >> 3) + half * 32;
        us8 o;
#pragma unroll
        for (int i = 0; i < 8; ++i) o[i] = f2bf(tile[kc * 8 + i][nrow]);
        *(us8*)(Wt + (size_t)(n0 + nrow) * K_DIM + k0 + kc * 8) = o;
    }
}

// ---------------------------------------------------------------- GEMM
// Restructured K-loop: global->VGPR->LDS double-buffer, ONE barrier/iter.
// Loads for tile t+2 issued at iter t, staged (cvt + ds_write) at iter t+1.
// No global_load_lds => no vmcnt(0) drain at the barrier (only lgkmcnt).
// A read as fp32 (cvt in-flight); B read as bf16 from pre-transposed Wt.
__global__ __launch_bounds__(256) void gemm_bf16(const float* __restrict__ A,
                                                 const unsigned short* __restrict__ Bt,
                                                 const float* __restrict__ bias,
                                                 float* __restrict__ C) {
    __shared__ __align__(16) unsigned short As[2][BM * BK];  // 2 x 8 KB
    __shared__ __align__(16) unsigned short Bs[2][BN * BK];  // 2 x 8 KB

    // XCD-aware supertile swizzle (as R2): 8x8 block supertiles per XCD
    const int bid = blockIdx.x;
    const int xcd = bid & 7;
    const int i_ = bid >> 3;
    const int st = xcd + 8 * (i_ >> 6);
    const int within = i_ & 63;
    const int m0 = ((st >> 2) * 8 + (within >> 3)) * BM;
    const int n0 = ((st & 3) * 8 + (within & 7)) * BN;

    const int tid = threadIdx.x;
    const int lane = tid & 63;
    const int wave = tid >> 6;
    const int wm = (wave >> 1) * 64;
    const int wn = (wave & 1) * 64;
    const int lrow = lane & 15;
    const int quad = lane >> 4;
    const int koff = quad * 8;

    f32x4 acc[4][4] = {};

    // per-thread staging map: us8 chunk0 row = tid>>2 (0..63), chunk1 row +64;
    // k-offset (tid&3)*8. LDS element offset = tid*8 (+2048 for chunk1).
    const int r0 = tid >> 2;
    const int c0 = tid & 3;
    const float* agp0 = A + (size_t)(m0 + r0) * K_DIM + c0 * 8;
    const float* agp1 = agp0 + (size_t)64 * K_DIM;
    const unsigned short* bgp0 = Bt + (size_t)(n0 + r0) * K_DIM + c0 * 8;
    const unsigned short* bgp1 = bgp0 + (size_t)64 * K_DIM;
    const int lofs = tid * 8;

    float4 ra0, ra1, ra2, ra3;  // A staging (fp32, 2 chunks)
    us8 rb0, rb1;               // B staging (bf16)

#define ISSUE(t)                                          \
    do {                                                  \
        const float* ap0 = agp0 + (t) * BK;               \
        ra0 = *(const float4*)ap0;                        \
        ra1 = *(const float4*)(ap0 + 4);                  \
        const float* ap1 = agp1 + (t) * BK;               \
        ra2 = *(const float4*)ap1;                        \
        ra3 = *(const float4*)(ap1 + 4);                  \
        rb0 = *(const us8*)(bgp0 + (t) * BK);             \
        rb1 = *(const us8*)(bgp1 + (t) * BK);             \
    } while (0)

#define STAGE(buf)                                        \
    do {                                                  \
        *(us8*)(As[buf] + lofs) = cvt8(ra0, ra1);         \
        *(us8*)(As[buf] + 2048 + lofs) = cvt8(ra2, ra3);  \
        *(us8*)(Bs[buf] + lofs) = rb0;                    \
        *(us8*)(Bs[buf] + 2048 + lofs) = rb1;             \
    } while (0)

    ISSUE(0);
    STAGE(0);
    ISSUE(1);
    __syncthreads();

    int cur = 0;
    for (int kt = 0; kt < KT; ++kt) {
        // LDS -> fragments (issued first: oldest in lgkm queue)
        bf16x8 af[4], bf[4];
#pragma unroll
        for (int i = 0; i < 4; ++i)
            af[i] = *(const bf16x8*)(As[cur] + (wm + i * 16 + lrow) * BK + koff);
#pragma unroll
        for (int j = 0; j < 4; ++j)
            bf[j] = *(const bf16x8*)(Bs[cur] + (wn + j * 16 + lrow) * BK + koff);

        // stage tile kt+1 (regs arrived ~1 iter ago) into the other buffer,
        // then refill regs for tile kt+2
        if (kt < KT - 1) STAGE(cur ^ 1);
        if (kt < KT - 2) ISSUE(kt + 2);

#pragma unroll
        for (int i = 0; i < 4; ++i)
#pragma unroll
            for (int j = 0; j < 4; ++j)
                acc[i][j] = __builtin_amdgcn_mfma_f32_16x16x32_bf16(af[i], bf[j], acc[i][j], 0, 0, 0);

        __syncthreads();  // lgkmcnt drain only — no vmcnt(0)
        cur ^= 1;
    }

    // C/D layout: col = lane&15, row = quad*4 + reg   [measured m89/m91]
#pragma unroll
    for (int j = 0; j < 4; ++j) {
        const int col = n0 + wn + j * 16 + lrow;
        const float bj = bias[col];
#pragma unroll
        for (int i = 0; i < 4; ++i) {
            const int rbase = m0 + wm + i * 16 + quad * 4;
#pragma unroll
            for (int r = 0; r < 4; ++r)
                C[(size_t)(rbase + r) * N_DIM + col] = acc[i][j][r] + bj;
        }
    }
#undef ISSUE
#undef STAGE
}

// ---------------------------------------------------------------- fallback (ws too small)
__global__ __launch_bounds__(256) void naive_gemm(const float* __restrict__ A,
                                                  const float* __restrict__ W,
                                                  const float* __restrict__ bias,
                                                  float* __restrict__ C) {
    const int col = blockIdx.x * 16 + threadIdx.x;
    const int row = blockIdx.y * 16 + threadIdx.y;
    float s = 0.f;
    for (int k = 0; k < K_DIM; ++k)
        s += A[(size_t)row * K_DIM + k] * W[(size_t)k * N_DIM + col];
    C[(size_t)row * N_DIM + col] = s + bias[col];
}

extern "C" void kernel_launch(void* const* d_in, const int* in_sizes, int n_in,
                              void* d_out, int out_size, void* d_ws, size_t ws_size,
                              hipStream_t stream) {
    const float* A = (const float*)d_in[0];
    const float* W = (const float*)d_in[1];
    const float* bias = (const float*)d_in[2];
    float* out = (float*)d_out;

    const size_t need = (size_t)N_DIM * K_DIM * sizeof(unsigned short);  // 33.5 MB
    if (ws_size >= need) {
        unsigned short* Wt = (unsigned short*)d_ws;
        prep<<<4096, 256, 0, stream>>>(W, Wt);
        gemm_bf16<<<(M_DIM / BM) * (N_DIM / BN), 256, 0, stream>>>(A, Wt, bias, out);
    } else {
        naive_gemm<<<dim3(N_DIM / 16, M_DIM / 16), dim3(16, 16), 0, stream>>>(A, W, bias, out);
    }
}